// Round 12
// baseline (32.257 us; speedup 1.0000x reference)
//
#include <hip/hip_runtime.h>
#include <hip/hip_bf16.h>
#include <math.h>

// Problem constants (fixed by setup_inputs)
constexpr int B_ = 16, S_ = 512, T_ = 4096, E_ = 256;

typedef __attribute__((ext_vector_type(8))) short short8;
typedef __attribute__((ext_vector_type(4))) short short4v;
typedef __attribute__((ext_vector_type(4))) float f32x4;

// Workspace: 1024 validation flags (4 per fused block), written every call
constexpr size_t FLAGS_OFF = 0;

// -ln(10000)/256
#define NEGC (-0.035977892f)

__device__ __forceinline__ unsigned pk_bf16(float a, float b) {
    __hip_bfloat162 h = __float22bfloat162_rn(make_float2(a, b));
    return *(unsigned*)&h;
}
__device__ __forceinline__ short bf16s(float x) {
    unsigned u = __float_as_uint(x);
    u += 0x7FFFu + ((u >> 16) & 1u);
    return (short)(u >> 16);
}
__device__ __forceinline__ float bf16f(short s) {
    return __uint_as_float(((unsigned)(unsigned short)s) << 16);
}

// ---------------------------------------------------------------------------
// Fused GEMM, full-row-store structure.
// Block = 2 phones x 16 batches x ALL 256 cols; 512 threads (8 waves);
// grid 256 (= CU count). N looped in 4x64-col chunks (Bs restaged, acc[ch]
// registers). Store phase: wave stores whole 1KB output rows, 8KB sequential
// per (batch,phone) -- matches the contiguity of the 6.4 TB/s fill kernel.
__global__ __launch_bounds__(512, 2) void k_fused(
    const float* __restrict__ enc, const float* __restrict__ W,
    const float* __restrict__ bpos,
    const float* __restrict__ pitch, const int* __restrict__ beats,
    const float* __restrict__ wpitch, const float* __restrict__ bpitch,
    const float* __restrict__ embb,
    const int* __restrict__ align, const int* __restrict__ text,
    int* __restrict__ flags, float* __restrict__ out)
{
    __shared__ __align__(16) short AP[48 * 256];   // 24KB: rows 0-31 enc (ph*16+b), 32-47 PE
    __shared__ __align__(16) char region[49408];   // {Bs 32KB + pl 16x260 f32} | {ew 32x260 f32}
    short* const Bs = (short*)region;              // 64 n-rows x 256 k bf16 (chunk)
    float* const pl = (float*)(region + 32768);    // [16][260] PEW full width
    float* const ew = (float*)region;              // [32][260] after pl consumed

    const int tid = threadIdx.x;
    const int i0 = blockIdx.x * 2;                 // phone pair base
    const int t0base = i0 * 8;
    const int wid = tid >> 6, lane = tid & 63;
    const int q = lane >> 4, c = lane & 15;

    // ---- inline validation: 256 transitions per block -> flags[v*4+wid] ----
    if (tid < 256) {
        const int id = blockIdx.x * 256 + tid;
        const int t = id & (T_ - 1), b = id >> 12;
        int bad = 0;
        if (t > 0) {
            const int prev = (t - 1) >> 3;
            const int a = align[id];
            const int expct = (a == text[b * S_ + prev]) ? prev : min(prev + 1, S_ - 1);
            if ((t >> 3) != expct) bad = 1;
        }
        const int anybad = __any(bad) ? 1 : 0;
        if (lane == 0) flags[blockIdx.x * 4 + wid] = anybad;   // unconditional
    }

    // ---- stage AP: threads 0-255 enc rows 0-31; threads 256-511 PE rows 32-47 ----
    if (tid < 256) {
        const int r = tid >> 3;                    // arow = ph*16 + b
        const int c32 = (tid & 7) * 32;
        const int b = r & 15, ph = r >> 4;
        const float* ap = enc + (size_t)(b * S_ + i0 + ph) * E_ + c32;
#pragma unroll
        for (int g = 0; g < 4; ++g) {
            float4 f0 = *(const float4*)(ap + g * 8);
            float4 f1 = *(const float4*)(ap + g * 8 + 4);
            union { short8 v8; unsigned u[4]; } cv;
            cv.u[0] = pk_bf16(f0.x, f0.y); cv.u[1] = pk_bf16(f0.z, f0.w);
            cv.u[2] = pk_bf16(f1.x, f1.y); cv.u[3] = pk_bf16(f1.z, f1.w);
            *(short8*)&AP[(r * 256 + c32 + g * 8) ^ ((r & 7) << 3)] = cv.v8;
        }
    } else {
        const int t2 = tid - 256;
        const int r = t2 >> 4;                     // PE row 0..15 (t = t0base + r)
        const int c16 = t2 & 15;
        const int ar = 32 + r;
        const float tf = (float)(t0base + r);
#pragma unroll
        for (int g = 0; g < 2; ++g) {
            union { short8 v8; unsigned u[4]; } cv;
#pragma unroll
            for (int m = 0; m < 4; ++m) {
                const int j2 = c16 * 8 + g * 4 + m;
                const float d = __expf((float)(2 * j2) * NEGC);
                float s, cc;
                __sincosf(tf * d, &s, &cc);
                cv.u[m] = pk_bf16(s, cc);
            }
            *(short8*)&AP[(ar * 256 + c16 * 16 + g * 8) ^ ((ar & 7) << 3)] = cv.v8;
        }
    }

    // ---- chunk loop: 4 x 64 cols; acc[ch] accumulates EW fragments ----
    const int rowg = wid >> 2, colg = wid & 3;     // phase-2 tile: rows 16*rowg, cols 16*colg
    f32x4 acc[4] = {{0.f,0.f,0.f,0.f},{0.f,0.f,0.f,0.f},
                    {0.f,0.f,0.f,0.f},{0.f,0.f,0.f,0.f}};
#pragma unroll
    for (int ch = 0; ch < 4; ++ch) {
        // stage Bs from fp32 W: cols [ch*64, ch*64+64), transpose + cvt
        {
            const int kk = tid >> 4;               // 0..31
            const int nn = (tid & 15) * 4;         // 0..60
#pragma unroll
            for (int p = 0; p < 8; ++p) {
                const int k = p * 32 + kk;
                const float4 w4 = *(const float4*)(W + (size_t)k * E_ + ch * 64 + nn);
                Bs[((nn + 0) * 256 + k) ^ (((nn + 0) & 7) << 3)] = bf16s(w4.x);
                Bs[((nn + 1) * 256 + k) ^ (((nn + 1) & 7) << 3)] = bf16s(w4.y);
                Bs[((nn + 2) * 256 + k) ^ (((nn + 2) & 7) << 3)] = bf16s(w4.z);
                Bs[((nn + 3) * 256 + k) ^ (((nn + 3) & 7) << 3)] = bf16s(w4.w);
            }
        }
        __syncthreads();

        // phase 1 (alternating half of waves): pl[0..15][ch*64 + (wid&3)*16 + c]
        if ((wid >> 2) == (ch & 1)) {
            const int ar = 32 + c;
            const int br = (wid & 3) * 16 + c;
            f32x4 p = {0.f, 0.f, 0.f, 0.f};
#pragma unroll
            for (int ks = 0; ks < 8; ++ks) {
                const int kidx = ks * 32 + q * 8;
                short8 a = *(const short8*)&AP[(ar * 256 + kidx) ^ ((ar & 7) << 3)];
                short8 b = *(const short8*)&Bs[(br * 256 + kidx) ^ ((br & 7) << 3)];
                p = __builtin_amdgcn_mfma_f32_16x16x32_bf16(a, b, p, 0, 0, 0);
            }
#pragma unroll
            for (int rr = 0; rr < 4; ++rr)
                pl[(q * 4 + rr) * 260 + ch * 64 + (wid & 3) * 16 + c] = p[rr];
        }
        // phase 2 (all waves): 16 rows x 16 cols tile of this chunk
        {
            const int ar = rowg * 16 + c;
            const int br = colg * 16 + c;
#pragma unroll
            for (int ks = 0; ks < 8; ++ks) {
                const int kidx = ks * 32 + q * 8;
                short8 a = *(const short8*)&AP[(ar * 256 + kidx) ^ ((ar & 7) << 3)];
                short8 b = *(const short8*)&Bs[(br * 256 + kidx) ^ ((br & 7) << 3)];
                acc[ch] = __builtin_amdgcn_mfma_f32_16x16x32_bf16(a, b, acc[ch], 0, 0, 0);
            }
        }
        __syncthreads();
    }

    // ---- pv preload (full pl rows for this wave's phone) + uniforms ----
    const int l4 = lane * 4;
    const int ph = wid >> 2;                       // store phase: arow = wid*4+ii, ph = arow>>4
    f32x4 pv[8];
#pragma unroll
    for (int d = 0; d < 8; ++d)
        pv[d] = *(const f32x4*)&pl[(ph * 8 + d) * 260 + l4];
    const f32x4 wp4 = *(const f32x4*)(wpitch + l4);
    const f32x4 cst = *(const f32x4*)(bpitch + l4) + *(const f32x4*)(bpos + l4);
    const f32x4 be0 = *(const f32x4*)(embb + l4);
    const f32x4 be1 = *(const f32x4*)(embb + E_ + l4);
    __syncthreads();   // pv reads done -> ew may overwrite Bs/pl

    // ---- transpose acc into full-width ew (D: row = 4q+rr, col = c) ----
#pragma unroll
    for (int ch = 0; ch < 4; ++ch)
#pragma unroll
        for (int rr = 0; rr < 4; ++rr)
            ew[(rowg * 16 + q * 4 + rr) * 260 + ch * 64 + colg * 16 + c] = acc[ch][rr];
    __syncthreads();

    // ---- store phase: wave w owns arows [4w, 4w+4); full 1KB contiguous rows ----
#pragma unroll
    for (int ii = 0; ii < 4; ++ii) {
        const int arow = wid * 4 + ii;
        const int b = arow & 15;
        // enc fold from AP (4 bf16 = one b64 read; l4%8 in {0,4} stays in XOR unit)
        const short4v sv = *(const short4v*)&AP[(arow * 256 + l4) ^ ((arow & 7) << 3)];
        const f32x4 e4 = {bf16f(sv[0]), bf16f(sv[1]), bf16f(sv[2]), bf16f(sv[3])};
        const f32x4 ewv = *(const f32x4*)&ew[arow * 260 + l4];
        const f32x4 base = e4 + ewv + cst;
        const size_t prow = (size_t)b * T_ + t0base + ph * 8;
        const float4 pi0 = *(const float4*)(pitch + prow);      // wave-uniform bcast
        const float4 pi1 = *(const float4*)(pitch + prow + 4);
        const int4  bt0 = *(const int4*)(beats + prow);
        const int4  bt1 = *(const int4*)(beats + prow + 4);
        const float pp[8] = {pi0.x, pi0.y, pi0.z, pi0.w, pi1.x, pi1.y, pi1.z, pi1.w};
        const int   bb[8] = {bt0.x, bt0.y, bt0.z, bt0.w, bt1.x, bt1.y, bt1.z, bt1.w};
#pragma unroll
        for (int d = 0; d < 8; ++d) {
            const f32x4 be = bb[d] ? be1 : be0;
            f32x4 o = base + pv[d] + pp[d] * wp4 + be;
            __builtin_nontemporal_store(o, (f32x4*)(out + (prow + d) * E_ + l4));
        }
    }
}

// ---------------------------------------------------------------------------
// Fixup: reads the 1024 flags written by k_fused. Clean (always, for this
// data): instant exit. Dirty: fp32-exact full recompute of out.
__global__ __launch_bounds__(256) void k_fixup(
    const float* __restrict__ enc, const int* __restrict__ align,
    const int* __restrict__ text, const float* __restrict__ pitch,
    const int* __restrict__ beats, const float* __restrict__ wpitch,
    const float* __restrict__ bpitch, const float* __restrict__ embb,
    const float* __restrict__ W, const float* __restrict__ bpos,
    const int* __restrict__ flags, float* __restrict__ out)
{
    __shared__ int s[4];
    __shared__ int idxl[256];
    const int tid = threadIdx.x;
    {
        const int4 f = ((const int4*)flags)[tid];    // 256 x int4 = 1024 flags
        const int o = f.x | f.y | f.z | f.w;
        const bool any = __any(o != 0);
        if ((tid & 63) == 0) s[tid >> 6] = any ? 1 : 0;
    }
    __syncthreads();
    if (!(s[0] | s[1] | s[2] | s[3])) return;

    // ---- dirty path (never for this data): exact fp32 recompute ----
    const int b = blockIdx.x >> 4;
    const int tseg = (blockIdx.x & 15) * 256;
    if (tid == 0) {
        int i = 0;
        if (tseg == 0) idxl[0] = 0;
        for (int t = 1; t < tseg + 256; ++t) {
            if (align[b * T_ + t] != text[b * S_ + i]) i = min(i + 1, S_ - 1);
            if (t >= tseg) idxl[t - tseg] = i;
        }
    }
    __syncthreads();
    const int col = tid;
    for (int tt = 0; tt < 256; ++tt) {
        const int t = tseg + tt;
        const int i = idxl[tt];
        const float* erow = enc + (size_t)(b * S_ + i) * E_;
        float acc = 0.f;
        for (int k2 = 0; k2 < 128; ++k2) {
            const float d = __expf((float)(2 * k2) * NEGC);
            float sn, cs;
            __sincosf((float)t * d, &sn, &cs);
            acc += (erow[2 * k2] + sn) * W[(2 * k2) * E_ + col]
                 + (erow[2 * k2 + 1] + cs) * W[(2 * k2 + 1) * E_ + col];
        }
        const float p = pitch[(size_t)b * T_ + t];
        const float be = beats[(size_t)b * T_ + t] ? embb[E_ + col] : embb[col];
        out[((size_t)b * T_ + t) * E_ + col] =
            erow[col] + acc + bpos[col] + p * wpitch[col] + bpitch[col] + be;
    }
}

// ---------------------------------------------------------------------------
extern "C" void kernel_launch(void* const* d_in, const int* in_sizes, int n_in,
                              void* d_out, int out_size, void* d_ws, size_t ws_size,
                              hipStream_t stream) {
    const float* enc    = (const float*)d_in[0];
    const int*   align  = (const int*)  d_in[1];
    const int*   text   = (const int*)  d_in[2];
    const float* pitch  = (const float*)d_in[3];
    const int*   beats  = (const int*)  d_in[4];
    const float* wpitch = (const float*)d_in[5];
    const float* bpitch = (const float*)d_in[6];
    const float* embb   = (const float*)d_in[7];
    const float* wpos   = (const float*)d_in[8];
    const float* bpos   = (const float*)d_in[9];
    float* out = (float*)d_out;

    int* flags = (int*)((char*)d_ws + FLAGS_OFF);

    hipLaunchKernelGGL(k_fused, dim3(S_ / 2), dim3(512), 0, stream,
                       enc, wpos, bpos, pitch, beats, wpitch, bpitch, embb,
                       align, text, flags, out);
    hipLaunchKernelGGL(k_fixup, dim3(256), dim3(256), 0, stream,
                       enc, align, text, pitch, beats, wpitch, bpitch, embb,
                       wpos, bpos, flags, out);
}

// Round 13
// 24.703 us; speedup vs baseline: 1.3058x; 1.3058x over previous
//
#include <hip/hip_runtime.h>
#include <hip/hip_bf16.h>
#include <math.h>

// Problem constants (fixed by setup_inputs)
constexpr int B_ = 16, S_ = 512, T_ = 4096, E_ = 256;

typedef __attribute__((ext_vector_type(8))) short short8;
typedef __attribute__((ext_vector_type(4))) float f32x4;

// Workspace: 1024 validation flags (2 per fused block), written every call
constexpr size_t FLAGS_OFF = 0;

// -ln(10000)/256
#define NEGC (-0.035977892f)

__device__ __forceinline__ unsigned pk_bf16(float a, float b) {
    __hip_bfloat162 h = __float22bfloat162_rn(make_float2(a, b));
    return *(unsigned*)&h;
}
__device__ __forceinline__ short bf16s(float x) {
    unsigned u = __float_as_uint(x);
    u += 0x7FFFu + ((u >> 16) & 1u);
    return (short)(u >> 16);
}
__device__ __forceinline__ float bf16f(short s) {
    return __uint_as_float(((unsigned)(unsigned short)s) << 16);
}

// Raw barrier: LDS-visibility only — does NOT drain vmcnt, so global stores
// issued before it stay in flight (safe: no cross-wave reads of `out`).
__device__ __forceinline__ void rawbar() {
    asm volatile("s_waitcnt lgkmcnt(0)" ::: "memory");
    __builtin_amdgcn_s_barrier();
    __builtin_amdgcn_sched_barrier(0);
}

// ---------------------------------------------------------------------------
// Fused GEMM (R11 structure + full global-load hoisting so chunk-0's store
// burst retires under chunk-1's compute; vmcnt is FIFO, so ANY global load
// after the stores would serialize on them — chunk 1 must touch only
// LDS/registers until its own stores).
__global__ __launch_bounds__(256, 2) void k_fused(
    const float* __restrict__ enc, const float* __restrict__ W,
    const float* __restrict__ bpos,
    const float* __restrict__ pitch, const int* __restrict__ beats,
    const float* __restrict__ wpitch, const float* __restrict__ bpitch,
    const float* __restrict__ embb,
    const int* __restrict__ align, const int* __restrict__ text,
    int* __restrict__ flags, float* __restrict__ out)
{
    __shared__ __align__(16) short As[64 * 256];     // 32KB enc tile bf16 (persistent)
    __shared__ __align__(16) short Ps[32 * 256];     // 16KB PE rows bf16 (persistent)
    __shared__ __align__(16) short Bs[32 * 256];     // 16KB W^T chunk slice
    __shared__ __align__(16) float scratch[64 * 36]; // 9KB  pl then ew per chunk

    const int tid = threadIdx.x;
    const int i0 = blockIdx.x * 4;                   // phone base
    const int n0base = blockIdx.y * 64;
    const int t0base = i0 * 8;
    const int v = blockIdx.x * 4 + blockIdx.y;       // 0..511

    // ---- inline validation: disjoint 128-transition slice of the global
    // recurrence induction. All 512 blocks together cover all B*T ids. ----
    if (tid < 128) {
        const int id = v * 128 + tid;
        const int t = id & (T_ - 1), b = id >> 12;
        int bad = 0;
        if (t > 0) {
            const int prev = (t - 1) >> 3;
            const int a = align[id];
            const int expct = (a == text[b * S_ + prev]) ? prev : min(prev + 1, S_ - 1);
            if ((t >> 3) != expct) bad = 1;
        }
        const int anybad = __any(bad) ? 1 : 0;
        if ((tid & 63) == 0) flags[v * 2 + (tid >> 6)] = anybad;  // unconditional
    }

    // ================= hoisted global loads (ALL pre-store) =================
    const int c8q = tid & 7, rgrp = tid >> 3;        // epilogue thread map
    const int j = rgrp & 3;                          // phone offset

    // pitch/beats for both row-passes (chunk-independent — identical both chunks)
    float4 pi0[2], pi1[2];
    int4   bt0[2], bt1[2];
#pragma unroll
    for (int p = 0; p < 2; ++p) {
        const int row = rgrp + 32 * p;
        const int bq = row >> 2;
        const size_t prow = (size_t)bq * T_ + t0base + j * 8;
        pi0[p] = *(const float4*)(pitch + prow);
        pi1[p] = *(const float4*)(pitch + prow + 4);
        bt0[p] = *(const int4*)(beats + prow);
        bt1[p] = *(const int4*)(beats + prow + 4);
    }
    // per-chunk epilogue uniforms
    f32x4 wp4[2], cst[2], be0[2], be1[2];
#pragma unroll
    for (int ch = 0; ch < 2; ++ch) {
        const int gc = n0base + ch * 32 + 4 * c8q;
        wp4[ch] = *(const f32x4*)(wpitch + gc);
        cst[ch] = *(const f32x4*)(bpitch + gc) + *(const f32x4*)(bpos + gc);
        be0[ch] = *(const f32x4*)(embb + gc);
        be1[ch] = *(const f32x4*)(embb + E_ + gc);
    }
    // chunk-1 W tile prefetch (staging for chunk 1 becomes cvt + ds_write only)
    const int kk = tid >> 3;                         // 0..31
    const int nn = (tid & 7) * 4;                    // 0..28
    float4 wr[8];
#pragma unroll
    for (int p = 0; p < 8; ++p)
        wr[p] = *(const float4*)(W + (size_t)(p * 32 + kk) * E_ + n0base + 32 + nn);

    // ---- stage As = enc rows 0..63 (row r: b = r>>2, phone = i0 + (r&3)) ----
    {
        const int r = tid >> 2, c4 = tid & 3;
        const float* ap = enc + (size_t)((r >> 2) * S_ + i0 + (r & 3)) * E_;
#pragma unroll
        for (int jj = 0; jj < 8; ++jj) {
            const int seg = c4 + 4 * jj;
            float4 f0 = *(const float4*)(ap + seg * 8);
            float4 f1 = *(const float4*)(ap + seg * 8 + 4);
            union { short8 v8; unsigned u[4]; } cv;
            cv.u[0] = pk_bf16(f0.x, f0.y);
            cv.u[1] = pk_bf16(f0.z, f0.w);
            cv.u[2] = pk_bf16(f1.x, f1.y);
            cv.u[3] = pk_bf16(f1.z, f1.w);
            *(short8*)&As[(r * 256 + seg * 8) ^ ((r & 7) << 3)] = cv.v8;
        }
    }
    // ---- stage Ps = PE rows 0..31 (on-the-fly sincos) ----
    {
        const int r = tid >> 3, c8 = tid & 7;
        const float tf = (float)(t0base + r);
#pragma unroll
        for (int jj = 0; jj < 4; ++jj) {
            const int seg = c8 * 4 + jj;
            union { short8 v8; unsigned u[4]; } cv;
#pragma unroll
            for (int m = 0; m < 4; ++m) {
                const int j2 = seg * 4 + m;
                const float d = __expf((float)(2 * j2) * NEGC);
                float s, c;
                __sincosf(tf * d, &s, &c);
                cv.u[m] = pk_bf16(s, c);
            }
            *(short8*)&Ps[(r * 256 + seg * 8) ^ ((r & 7) << 3)] = cv.v8;
        }
    }

    const int wid = tid >> 6, lane = tid & 63;
    const int q = lane >> 4, c = lane & 15;
    float* const pl = scratch;                       // [4][16][16] patches
    float* const ew = scratch;                       // [64][36] after pl consumed

#pragma unroll
    for (int chunk = 0; chunk < 2; ++chunk) {
        const int n0 = n0base + chunk * 32;

        // ---- stage Bs: chunk 0 from global W; chunk 1 from prefetched regs ----
        {
#pragma unroll
            for (int p = 0; p < 8; ++p) {
                const int k = p * 32 + kk;
                float4 w4;
                if (chunk == 0) w4 = *(const float4*)(W + (size_t)k * E_ + n0 + nn);
                else            w4 = wr[p];
                Bs[((nn + 0) * 256 + k) ^ (((nn + 0) & 7) << 3)] = bf16s(w4.x);
                Bs[((nn + 1) * 256 + k) ^ (((nn + 1) & 7) << 3)] = bf16s(w4.y);
                Bs[((nn + 2) * 256 + k) ^ (((nn + 2) & 7) << 3)] = bf16s(w4.z);
                Bs[((nn + 3) * 256 + k) ^ (((nn + 3) & 7) << 3)] = bf16s(w4.w);
            }
        }
        if (chunk == 0) __syncthreads(); else rawbar();   // staging visible

        // ---- phase 1 MFMA: 32x32 PEW slice, wave (tq, nq) = 16t x 16n ----
        {
            const int tq = wid >> 1, nqp = wid & 1;
            const int ar = tq * 16 + c;
            const int br = nqp * 16 + c;
            f32x4 p = {0.f, 0.f, 0.f, 0.f};
#pragma unroll
            for (int ks = 0; ks < 8; ++ks) {
                const int kidx = ks * 32 + q * 8;
                short8 a = *(const short8*)&Ps[(ar * 256 + kidx) ^ ((ar & 7) << 3)];
                short8 b = *(const short8*)&Bs[(br * 256 + kidx) ^ ((br & 7) << 3)];
                p = __builtin_amdgcn_mfma_f32_16x16x32_bf16(a, b, p, 0, 0, 0);
            }
#pragma unroll
            for (int rr = 0; rr < 4; ++rr)
                pl[(tq * 2 + nqp) * 256 + (q * 4 + rr) * 16 + c] = p[rr];
        }
        if (chunk == 0) __syncthreads(); else rawbar();   // pl visible

        // ---- phase 2 MFMA: wave (mq, nq) = 32 enc-rows x 16 cols ----
        const int mq = wid >> 1, nq = wid & 1;
        const int ra0 = mq * 32 + c, ra1 = ra0 + 16;
        const int rb = nq * 16 + c;
        f32x4 acc0 = {0.f, 0.f, 0.f, 0.f}, acc1 = {0.f, 0.f, 0.f, 0.f};
#pragma unroll
        for (int ks = 0; ks < 8; ++ks) {
            const int kidx = ks * 32 + q * 8;
            short8 a0 = *(const short8*)&As[(ra0 * 256 + kidx) ^ ((ra0 & 7) << 3)];
            short8 a1 = *(const short8*)&As[(ra1 * 256 + kidx) ^ ((ra1 & 7) << 3)];
            short8 b  = *(const short8*)&Bs[(rb * 256 + kidx) ^ ((rb & 7) << 3)];
            acc0 = __builtin_amdgcn_mfma_f32_16x16x32_bf16(a0, b, acc0, 0, 0, 0);
            acc1 = __builtin_amdgcn_mfma_f32_16x16x32_bf16(a1, b, acc1, 0, 0, 0);
        }

        // ---- fold enc into acc (from As; epilogue has no enc re-read) ----
        {
            const int gc2 = n0 + nq * 16 + c;        // absolute output col = As k-index
#pragma unroll
            for (int rr = 0; rr < 4; ++rr) {
                const int r0 = mq * 32 + q * 4 + rr, r1 = r0 + 16;
                acc0[rr] += bf16f(As[(r0 * 256 + gc2) ^ ((r0 & 7) << 3)]);
                acc1[rr] += bf16f(As[(r1 * 256 + gc2) ^ ((r1 & 7) << 3)]);
            }
        }

        // ---- pv pre-read from pl (LDS only) ----
        const int gc = n0 + 4 * c8q;
        f32x4 pv[8];
#pragma unroll
        for (int d = 0; d < 8; ++d) {
            const int tl = j * 8 + d;
            pv[d] = *(const f32x4*)&pl[((tl >> 4) * 2 + (c8q >> 2)) * 256
                                       + (tl & 15) * 16 + ((4 * c8q) & 15)];
        }
        if (chunk == 0) __syncthreads(); else rawbar();   // all pl + Bs reads done

        // ---- transpose acc through LDS (D: row = 4q+rr, col = c); stride 36 ----
#pragma unroll
        for (int rr = 0; rr < 4; ++rr) {
            ew[(mq * 32 + q * 4 + rr) * 36 + nq * 16 + c]      = acc0[rr];
            ew[(mq * 32 + 16 + q * 4 + rr) * 36 + nq * 16 + c] = acc1[rr];
        }
        if (chunk == 0) __syncthreads(); else rawbar();   // ew visible

        // ---- epilogue: pure regs+LDS; nt stores (stay in flight into chunk 1) ----
#pragma unroll
        for (int p = 0; p < 2; ++p) {
            const int row = rgrp + 32 * p;
            const int bq = row >> 2;
            const size_t prow = (size_t)bq * T_ + t0base + j * 8;
            const f32x4 ewv = *(const f32x4*)&ew[row * 36 + 4 * c8q];
            const f32x4 base = ewv + cst[chunk];
            const float pp[8] = {pi0[p].x, pi0[p].y, pi0[p].z, pi0[p].w,
                                 pi1[p].x, pi1[p].y, pi1[p].z, pi1[p].w};
            const int   bb[8] = {bt0[p].x, bt0[p].y, bt0[p].z, bt0[p].w,
                                 bt1[p].x, bt1[p].y, bt1[p].z, bt1[p].w};
#pragma unroll
            for (int d = 0; d < 8; ++d) {
                const f32x4 be = bb[d] ? be1[chunk] : be0[chunk];
                f32x4 o = base + pv[d] + pp[d] * wp4[chunk] + be;
                __builtin_nontemporal_store(o, (f32x4*)(out + (prow + d) * E_ + gc));
            }
        }
        if (chunk == 0) rawbar();   // scratch/Bs free for chunk 1; stores in flight
    }
}

// ---------------------------------------------------------------------------
// Fixup: reads the 1024 flags written by k_fused. Clean (always, for this
// data): instant exit. Dirty: fp32-exact full recompute of out.
__global__ __launch_bounds__(256) void k_fixup(
    const float* __restrict__ enc, const int* __restrict__ align,
    const int* __restrict__ text, const float* __restrict__ pitch,
    const int* __restrict__ beats, const float* __restrict__ wpitch,
    const float* __restrict__ bpitch, const float* __restrict__ embb,
    const float* __restrict__ W, const float* __restrict__ bpos,
    const int* __restrict__ flags, float* __restrict__ out)
{
    __shared__ int s[4];
    __shared__ int idxl[256];
    const int tid = threadIdx.x;
    {
        const int4 f = ((const int4*)flags)[tid];    // 256 x int4 = 1024 flags
        const int o = f.x | f.y | f.z | f.w;
        const bool any = __any(o != 0);
        if ((tid & 63) == 0) s[tid >> 6] = any ? 1 : 0;
    }
    __syncthreads();
    if (!(s[0] | s[1] | s[2] | s[3])) return;

    // ---- dirty path (never for this data): exact fp32 recompute ----
    const int b = blockIdx.x >> 4;
    const int tseg = (blockIdx.x & 15) * 256;
    if (tid == 0) {
        int i = 0;
        if (tseg == 0) idxl[0] = 0;
        for (int t = 1; t < tseg + 256; ++t) {
            if (align[b * T_ + t] != text[b * S_ + i]) i = min(i + 1, S_ - 1);
            if (t >= tseg) idxl[t - tseg] = i;
        }
    }
    __syncthreads();
    const int col = tid;
    for (int tt = 0; tt < 256; ++tt) {
        const int t = tseg + tt;
        const int i = idxl[tt];
        const float* erow = enc + (size_t)(b * S_ + i) * E_;
        float acc = 0.f;
        for (int k2 = 0; k2 < 128; ++k2) {
            const float d = __expf((float)(2 * k2) * NEGC);
            float sn, cs;
            __sincosf((float)t * d, &sn, &cs);
            acc += (erow[2 * k2] + sn) * W[(2 * k2) * E_ + col]
                 + (erow[2 * k2 + 1] + cs) * W[(2 * k2 + 1) * E_ + col];
        }
        const float p = pitch[(size_t)b * T_ + t];
        const float be = beats[(size_t)b * T_ + t] ? embb[E_ + col] : embb[col];
        out[((size_t)b * T_ + t) * E_ + col] =
            erow[col] + acc + bpos[col] + p * wpitch[col] + bpitch[col] + be;
    }
}

// ---------------------------------------------------------------------------
extern "C" void kernel_launch(void* const* d_in, const int* in_sizes, int n_in,
                              void* d_out, int out_size, void* d_ws, size_t ws_size,
                              hipStream_t stream) {
    const float* enc    = (const float*)d_in[0];
    const int*   align  = (const int*)  d_in[1];
    const int*   text   = (const int*)  d_in[2];
    const float* pitch  = (const float*)d_in[3];
    const int*   beats  = (const int*)  d_in[4];
    const float* wpitch = (const float*)d_in[5];
    const float* bpitch = (const float*)d_in[6];
    const float* embb   = (const float*)d_in[7];
    const float* wpos   = (const float*)d_in[8];
    const float* bpos   = (const float*)d_in[9];
    float* out = (float*)d_out;

    int* flags = (int*)((char*)d_ws + FLAGS_OFF);

    hipLaunchKernelGGL(k_fused, dim3(S_ / 4, 4), dim3(256), 0, stream,
                       enc, wpos, bpos, pitch, beats, wpitch, bpitch, embb,
                       align, text, flags, out);
    hipLaunchKernelGGL(k_fixup, dim3(256), dim3(256), 0, stream,
                       enc, align, text, pitch, beats, wpitch, bpitch, embb,
                       wpos, bpos, flags, out);
}

// Round 14
// 23.555 us; speedup vs baseline: 1.3694x; 1.0488x over previous
//
#include <hip/hip_runtime.h>
#include <hip/hip_bf16.h>
#include <math.h>

// Problem constants (fixed by setup_inputs)
constexpr int B_ = 16, S_ = 512, T_ = 4096, E_ = 256;

typedef __attribute__((ext_vector_type(8))) short short8;
typedef __attribute__((ext_vector_type(4))) float f32x4;

// Workspace: 1024 validation flags (2 per fused block), written every call
constexpr size_t FLAGS_OFF = 0;

// -ln(10000)/256
#define NEGC (-0.035977892f)

__device__ __forceinline__ unsigned pk_bf16(float a, float b) {
    __hip_bfloat162 h = __float22bfloat162_rn(make_float2(a, b));
    return *(unsigned*)&h;
}
__device__ __forceinline__ short bf16s(float x) {
    unsigned u = __float_as_uint(x);
    u += 0x7FFFu + ((u >> 16) & 1u);
    return (short)(u >> 16);
}
__device__ __forceinline__ float bf16f(short s) {
    return __uint_as_float(((unsigned)(unsigned short)s) << 16);
}

// Raw barrier: LDS-visibility only — does NOT drain vmcnt, so global stores
// issued before it stay in flight (safe: no cross-wave reads of `out`).
__device__ __forceinline__ void rawbar() {
    asm volatile("s_waitcnt lgkmcnt(0)" ::: "memory");
    __builtin_amdgcn_s_barrier();
    __builtin_amdgcn_sched_barrier(0);
}

// ---------------------------------------------------------------------------
// Fused GEMM (R11 structure; all chunk-1/epilogue global loads issued in the
// window between chunk-0 phase-2 and chunk-0's store burst. vmcnt is FIFO:
// a load issued AFTER stores waits for them — so chunk 1 is pure reg/LDS and
// chunk-0's stores retire under chunk-1's compute).
__global__ __launch_bounds__(256, 2) void k_fused(
    const float* __restrict__ enc, const float* __restrict__ W,
    const float* __restrict__ bpos,
    const float* __restrict__ pitch, const int* __restrict__ beats,
    const float* __restrict__ wpitch, const float* __restrict__ bpitch,
    const float* __restrict__ embb,
    const int* __restrict__ align, const int* __restrict__ text,
    int* __restrict__ flags, float* __restrict__ out)
{
    __shared__ __align__(16) short As[64 * 256];     // 32KB enc tile bf16 (persistent)
    __shared__ __align__(16) short Ps[32 * 256];     // 16KB PE rows bf16 (persistent)
    __shared__ __align__(16) short Bs[32 * 256];     // 16KB W^T chunk slice
    __shared__ __align__(16) float scratch[64 * 36]; // 9KB  pl then ew per chunk

    const int tid = threadIdx.x;
    const int i0 = blockIdx.x * 4;                   // phone base
    const int n0base = blockIdx.y * 64;
    const int t0base = i0 * 8;
    const int v = blockIdx.x * 4 + blockIdx.y;       // 0..511

    // ---- inline validation: disjoint 128-transition slice of the global
    // recurrence induction. All 512 blocks together cover all B*T ids. ----
    if (tid < 128) {
        const int id = v * 128 + tid;
        const int t = id & (T_ - 1), b = id >> 12;
        int bad = 0;
        if (t > 0) {
            const int prev = (t - 1) >> 3;
            const int a = align[id];
            const int expct = (a == text[b * S_ + prev]) ? prev : min(prev + 1, S_ - 1);
            if ((t >> 3) != expct) bad = 1;
        }
        const int anybad = __any(bad) ? 1 : 0;
        if ((tid & 63) == 0) flags[v * 2 + (tid >> 6)] = anybad;  // unconditional
    }

    // ---- stage As = enc rows 0..63 (row r: b = r>>2, phone = i0 + (r&3)) ----
    {
        const int r = tid >> 2, c4 = tid & 3;
        const float* ap = enc + (size_t)((r >> 2) * S_ + i0 + (r & 3)) * E_;
#pragma unroll
        for (int jj = 0; jj < 8; ++jj) {
            const int seg = c4 + 4 * jj;
            float4 f0 = *(const float4*)(ap + seg * 8);
            float4 f1 = *(const float4*)(ap + seg * 8 + 4);
            union { short8 v8; unsigned u[4]; } cv;
            cv.u[0] = pk_bf16(f0.x, f0.y);
            cv.u[1] = pk_bf16(f0.z, f0.w);
            cv.u[2] = pk_bf16(f1.x, f1.y);
            cv.u[3] = pk_bf16(f1.z, f1.w);
            *(short8*)&As[(r * 256 + seg * 8) ^ ((r & 7) << 3)] = cv.v8;
        }
    }
    // ---- stage Ps = PE rows 0..31 (on-the-fly sincos) ----
    {
        const int r = tid >> 3, c8 = tid & 7;
        const float tf = (float)(t0base + r);
#pragma unroll
        for (int jj = 0; jj < 4; ++jj) {
            const int seg = c8 * 4 + jj;
            union { short8 v8; unsigned u[4]; } cv;
#pragma unroll
            for (int m = 0; m < 4; ++m) {
                const int j2 = seg * 4 + m;
                const float d = __expf((float)(2 * j2) * NEGC);
                float s, c;
                __sincosf(tf * d, &s, &c);
                cv.u[m] = pk_bf16(s, c);
            }
            *(short8*)&Ps[(r * 256 + seg * 8) ^ ((r & 7) << 3)] = cv.v8;
        }
    }

    const int wid = tid >> 6, lane = tid & 63;
    const int q = lane >> 4, c = lane & 15;
    const int c8q = tid & 7, rgrp = tid >> 3;        // epilogue thread map
    const int j = rgrp & 3;                          // phone offset
    const int kk = tid >> 3;                         // Bs staging: k offset
    const int nn = (tid & 7) * 4;                    //             rel. n
    float* const pl = scratch;                       // [4][16][16] patches
    float* const ew = scratch;                       // [64][36] after pl consumed

    // persistent epilogue/prefetch registers (written in chunk 0, pre-store)
    float4 pi0[2], pi1[2];
    int4   bt0[2], bt1[2];
    f32x4  wp4[2], cst[2], be0[2], be1[2];
    float4 wr[8];

#pragma unroll
    for (int chunk = 0; chunk < 2; ++chunk) {
        const int n0 = n0base + chunk * 32;

        // ---- stage Bs: chunk 0 from global W; chunk 1 from prefetched regs ----
        {
#pragma unroll
            for (int p = 0; p < 8; ++p) {
                const int k = p * 32 + kk;
                float4 w4;
                if (chunk == 0) w4 = *(const float4*)(W + (size_t)k * E_ + n0 + nn);
                else            w4 = wr[p];
                Bs[((nn + 0) * 256 + k) ^ (((nn + 0) & 7) << 3)] = bf16s(w4.x);
                Bs[((nn + 1) * 256 + k) ^ (((nn + 1) & 7) << 3)] = bf16s(w4.y);
                Bs[((nn + 2) * 256 + k) ^ (((nn + 2) & 7) << 3)] = bf16s(w4.z);
                Bs[((nn + 3) * 256 + k) ^ (((nn + 3) & 7) << 3)] = bf16s(w4.w);
            }
        }
        if (chunk == 0) __syncthreads(); else rawbar();   // staging visible

        // ---- phase 1 MFMA: 32x32 PEW slice, wave (tq, nq) = 16t x 16n ----
        {
            const int tq = wid >> 1, nqp = wid & 1;
            const int ar = tq * 16 + c;
            const int br = nqp * 16 + c;
            f32x4 p = {0.f, 0.f, 0.f, 0.f};
#pragma unroll
            for (int ks = 0; ks < 8; ++ks) {
                const int kidx = ks * 32 + q * 8;
                short8 a = *(const short8*)&Ps[(ar * 256 + kidx) ^ ((ar & 7) << 3)];
                short8 b = *(const short8*)&Bs[(br * 256 + kidx) ^ ((br & 7) << 3)];
                p = __builtin_amdgcn_mfma_f32_16x16x32_bf16(a, b, p, 0, 0, 0);
            }
#pragma unroll
            for (int rr = 0; rr < 4; ++rr)
                pl[(tq * 2 + nqp) * 256 + (q * 4 + rr) * 16 + c] = p[rr];
        }
        if (chunk == 0) __syncthreads(); else rawbar();   // pl visible

        // ---- phase 2 MFMA: wave (mq, nq) = 32 enc-rows x 16 cols ----
        const int mq = wid >> 1, nq = wid & 1;
        const int ra0 = mq * 32 + c, ra1 = ra0 + 16;
        const int rb = nq * 16 + c;
        f32x4 acc0 = {0.f, 0.f, 0.f, 0.f}, acc1 = {0.f, 0.f, 0.f, 0.f};
#pragma unroll
        for (int ks = 0; ks < 8; ++ks) {
            const int kidx = ks * 32 + q * 8;
            short8 a0 = *(const short8*)&As[(ra0 * 256 + kidx) ^ ((ra0 & 7) << 3)];
            short8 a1 = *(const short8*)&As[(ra1 * 256 + kidx) ^ ((ra1 & 7) << 3)];
            short8 b  = *(const short8*)&Bs[(rb * 256 + kidx) ^ ((rb & 7) << 3)];
            acc0 = __builtin_amdgcn_mfma_f32_16x16x32_bf16(a0, b, acc0, 0, 0, 0);
            acc1 = __builtin_amdgcn_mfma_f32_16x16x32_bf16(a1, b, acc1, 0, 0, 0);
        }

        // ---- fold enc into acc (from As; epilogue has no enc re-read) ----
        {
            const int gc2 = n0 + nq * 16 + c;        // absolute output col = As k-index
#pragma unroll
            for (int rr = 0; rr < 4; ++rr) {
                const int r0 = mq * 32 + q * 4 + rr, r1 = r0 + 16;
                acc0[rr] += bf16f(As[(r0 * 256 + gc2) ^ ((r0 & 7) << 3)]);
                acc1[rr] += bf16f(As[(r1 * 256 + gc2) ^ ((r1 & 7) << 3)]);
            }
        }

        // ---- pv pre-read from pl (LDS only) ----
        const int gc = n0 + 4 * c8q;
        f32x4 pv[8];
#pragma unroll
        for (int d = 0; d < 8; ++d) {
            const int tl = j * 8 + d;
            pv[d] = *(const f32x4*)&pl[((tl >> 4) * 2 + (c8q >> 2)) * 256
                                       + (tl & 15) * 16 + ((4 * c8q) & 15)];
        }

        // ==== pre-store global-load window (chunk 0 only): everything the
        // rest of the kernel will ever need from global. These retire at the
        // next __syncthreads (which drains vmcnt anyway); chunk-0's stores
        // and all of chunk 1 then run with ZERO trailing global loads. ====
        if (chunk == 0) {
#pragma unroll
            for (int p = 0; p < 2; ++p) {
                const int row = rgrp + 32 * p;
                const int bq = row >> 2;
                const size_t prow = (size_t)bq * T_ + t0base + j * 8;
                pi0[p] = *(const float4*)(pitch + prow);
                pi1[p] = *(const float4*)(pitch + prow + 4);
                bt0[p] = *(const int4*)(beats + prow);
                bt1[p] = *(const int4*)(beats + prow + 4);
            }
#pragma unroll
            for (int ch2 = 0; ch2 < 2; ++ch2) {
                const int gcu = n0base + ch2 * 32 + 4 * c8q;
                wp4[ch2] = *(const f32x4*)(wpitch + gcu);
                cst[ch2] = *(const f32x4*)(bpitch + gcu) + *(const f32x4*)(bpos + gcu);
                be0[ch2] = *(const f32x4*)(embb + gcu);
                be1[ch2] = *(const f32x4*)(embb + E_ + gcu);
            }
#pragma unroll
            for (int p = 0; p < 8; ++p)
                wr[p] = *(const float4*)(W + (size_t)(p * 32 + kk) * E_ + n0base + 32 + nn);
        }
        if (chunk == 0) __syncthreads(); else rawbar();   // all pl + Bs reads done

        // ---- transpose acc through LDS (D: row = 4q+rr, col = c); stride 36 ----
#pragma unroll
        for (int rr = 0; rr < 4; ++rr) {
            ew[(mq * 32 + q * 4 + rr) * 36 + nq * 16 + c]      = acc0[rr];
            ew[(mq * 32 + 16 + q * 4 + rr) * 36 + nq * 16 + c] = acc1[rr];
        }
        if (chunk == 0) __syncthreads(); else rawbar();   // ew visible

        // ---- epilogue: pure regs+LDS; nt stores (stay in flight onward) ----
#pragma unroll
        for (int p = 0; p < 2; ++p) {
            const int row = rgrp + 32 * p;
            const int bq = row >> 2;
            const size_t prow = (size_t)bq * T_ + t0base + j * 8;
            const f32x4 ewv = *(const f32x4*)&ew[row * 36 + 4 * c8q];
            const f32x4 base = ewv + cst[chunk];
            const float pp[8] = {pi0[p].x, pi0[p].y, pi0[p].z, pi0[p].w,
                                 pi1[p].x, pi1[p].y, pi1[p].z, pi1[p].w};
            const int   bb[8] = {bt0[p].x, bt0[p].y, bt0[p].z, bt0[p].w,
                                 bt1[p].x, bt1[p].y, bt1[p].z, bt1[p].w};
#pragma unroll
            for (int d = 0; d < 8; ++d) {
                const f32x4 be = bb[d] ? be1[chunk] : be0[chunk];
                f32x4 o = base + pv[d] + pp[d] * wp4[chunk] + be;
                __builtin_nontemporal_store(o, (f32x4*)(out + (prow + d) * E_ + gc));
            }
        }
        if (chunk == 0) rawbar();   // scratch/Bs free for chunk 1; stores in flight
    }
}

// ---------------------------------------------------------------------------
// Fixup: reads the 1024 flags written by k_fused. Clean (always, for this
// data): instant exit. Dirty: fp32-exact full recompute of out.
__global__ __launch_bounds__(256) void k_fixup(
    const float* __restrict__ enc, const int* __restrict__ align,
    const int* __restrict__ text, const float* __restrict__ pitch,
    const int* __restrict__ beats, const float* __restrict__ wpitch,
    const float* __restrict__ bpitch, const float* __restrict__ embb,
    const float* __restrict__ W, const float* __restrict__ bpos,
    const int* __restrict__ flags, float* __restrict__ out)
{
    __shared__ int s[4];
    __shared__ int idxl[256];
    const int tid = threadIdx.x;
    {
        const int4 f = ((const int4*)flags)[tid];    // 256 x int4 = 1024 flags
        const int o = f.x | f.y | f.z | f.w;
        const bool any = __any(o != 0);
        if ((tid & 63) == 0) s[tid >> 6] = any ? 1 : 0;
    }
    __syncthreads();
    if (!(s[0] | s[1] | s[2] | s[3])) return;

    // ---- dirty path (never for this data): exact fp32 recompute ----
    const int b = blockIdx.x >> 4;
    const int tseg = (blockIdx.x & 15) * 256;
    if (tid == 0) {
        int i = 0;
        if (tseg == 0) idxl[0] = 0;
        for (int t = 1; t < tseg + 256; ++t) {
            if (align[b * T_ + t] != text[b * S_ + i]) i = min(i + 1, S_ - 1);
            if (t >= tseg) idxl[t - tseg] = i;
        }
    }
    __syncthreads();
    const int col = tid;
    for (int tt = 0; tt < 256; ++tt) {
        const int t = tseg + tt;
        const int i = idxl[tt];
        const float* erow = enc + (size_t)(b * S_ + i) * E_;
        float acc = 0.f;
        for (int k2 = 0; k2 < 128; ++k2) {
            const float d = __expf((float)(2 * k2) * NEGC);
            float sn, cs;
            __sincosf((float)t * d, &sn, &cs);
            acc += (erow[2 * k2] + sn) * W[(2 * k2) * E_ + col]
                 + (erow[2 * k2 + 1] + cs) * W[(2 * k2 + 1) * E_ + col];
        }
        const float p = pitch[(size_t)b * T_ + t];
        const float be = beats[(size_t)b * T_ + t] ? embb[E_ + col] : embb[col];
        out[((size_t)b * T_ + t) * E_ + col] =
            erow[col] + acc + bpos[col] + p * wpitch[col] + bpitch[col] + be;
    }
}

// ---------------------------------------------------------------------------
extern "C" void kernel_launch(void* const* d_in, const int* in_sizes, int n_in,
                              void* d_out, int out_size, void* d_ws, size_t ws_size,
                              hipStream_t stream) {
    const float* enc    = (const float*)d_in[0];
    const int*   align  = (const int*)  d_in[1];
    const int*   text   = (const int*)  d_in[2];
    const float* pitch  = (const float*)d_in[3];
    const int*   beats  = (const int*)  d_in[4];
    const float* wpitch = (const float*)d_in[5];
    const float* bpitch = (const float*)d_in[6];
    const float* embb   = (const float*)d_in[7];
    const float* wpos   = (const float*)d_in[8];
    const float* bpos   = (const float*)d_in[9];
    float* out = (float*)d_out;

    int* flags = (int*)((char*)d_ws + FLAGS_OFF);

    hipLaunchKernelGGL(k_fused, dim3(S_ / 4, 4), dim3(256), 0, stream,
                       enc, wpos, bpos, pitch, beats, wpitch, bpitch, embb,
                       align, text, flags, out);
    hipLaunchKernelGGL(k_fixup, dim3(256), dim3(256), 0, stream,
                       enc, align, text, pitch, beats, wpitch, bpitch, embb,
                       wpos, bpos, flags, out);
}